// Round 1
// baseline (244.507 us; speedup 1.0000x reference)
//
#include <hip/hip_runtime.h>
#include <math.h>

// Quadrotor dynamics, B=2^20 independent 32-float AoS rows.
// R1: coalesced LDS staging fixed VMEM transactions (247.8 us).
// R2 (this): kernel was still 5.5x above the 45us HBM floor -> theory:
// VGPR-pressure / spill bound (k1..k4 all live = 52 floats, s[32]+o[32]).
// Fixes: (a) RK4 accumulator form, (b) integrate only the 7 coupled states
// (quat+omega); v_dot is stage-constant so pos/v have exact closed forms,
// (c) operate field-wise out of the thread's own LDS row -- passthrough
// floats never touch registers, (d) __launch_bounds__(256,4) -> <=128 VGPR,
// 4 blocks/CU (LDS 4*36KB=144KB <= 160KB).

#define INV_MASSF  (1.0f / 1.5f)
#define GRAVF      9.81f
#define KDF        0.1f
#define KHF        0.01f
#define JXF        0.0211f
#define JYF        0.0219f
#define JZF        0.0366f
#define JIXF       (1.0f / 0.0211f)
#define JIYF       (1.0f / 0.0219f)
#define JIZF       (1.0f / 0.0366f)
#define PI_2F      1.57079632679489661923f

#define ROWS    256          // threads (rows) per block
#define STRIDE  36           // padded LDS row stride in floats (144B, %16==0)

__device__ __forceinline__ float clamp1(float x) {
    return fminf(fmaxf(x, -1.0f), 1.0f);
}

// derivative of the coupled 7-state block: x = {qw,qx,qy,qz, p,q,r}
__device__ __forceinline__ void qw_deriv(const float x[7],
                                         float mx, float my, float mz,
                                         float k[7]) {
    const float ew = x[0], ex = x[1], ey = x[2], ez = x[3];
    const float p = x[4], q = x[5], r = x[6];
    k[0] = 0.5f * (-ex * p - ey * q - ez * r);
    k[1] = 0.5f * ( ew * p + ey * r - ez * q);
    k[2] = 0.5f * ( ew * q - ex * r + ez * p);
    k[3] = 0.5f * ( ew * r + ex * q - ey * p);
    const float Jwx = JXF * p, Jwy = JYF * q, Jwz = JZF * r;
    k[4] = (mx - (q * Jwz - r * Jwy)) * JIXF;
    k[5] = (my - (r * Jwx - p * Jwz)) * JIYF;
    k[6] = (mz - (p * Jwy - q * Jwx)) * JIZF;
}

__global__ __launch_bounds__(ROWS, 4) void qd_dynamics_kernel(
    const float* __restrict__ state,
    const float* __restrict__ delta,
    const float* __restrict__ G1,
    const float* __restrict__ dtp,
    float* __restrict__ out,
    int B)
{
    __shared__ float lds[ROWS * STRIDE];   // 36 KB

    const int tid = threadIdx.x;
    const int row0 = blockIdx.x * ROWS;
    const bool full = (row0 + ROWS) <= B;

    const float dt = dtp[0];
    const float h2 = 0.5f * dt;

    // ---- coalesced stage-in ----
    float4 dl;
    if (full) {
        const float4* gp4 = (const float4*)(state + (size_t)row0 * 32);
        #pragma unroll
        for (int i = 0; i < 8; ++i) {
            const int f4 = i * ROWS + tid;
            const int r  = f4 >> 3;          // row in tile
            const int c4 = f4 & 7;           // float4 slot in row
            *(float4*)&lds[r * STRIDE + c4 * 4] = gp4[f4];
        }
        dl = ((const float4*)delta)[row0 + tid];
    } else {
        const int last = B - 1;
        #pragma unroll
        for (int i = 0; i < 8; ++i) {
            const int f4 = i * ROWS + tid;
            const int r  = f4 >> 3;
            const int c4 = f4 & 7;
            const int gr = min(row0 + r, last);
            *(float4*)&lds[r * STRIDE + c4 * 4] =
                ((const float4*)state)[(size_t)gr * 8 + c4];
        }
        dl = ((const float4*)delta)[min(row0 + tid, last)];
    }
    __syncthreads();

    // ---- motor mixing: tt = G1 @ clip(delta)^2 (g regs die immediately) ----
    float T, Mx, My, Mz;
    {
        float d0 = fminf(fmaxf(dl.x, 0.0f), 1000.0f);
        float d1 = fminf(fmaxf(dl.y, 0.0f), 1000.0f);
        float d2 = fminf(fmaxf(dl.z, 0.0f), 1000.0f);
        float d3 = fminf(fmaxf(dl.w, 0.0f), 1000.0f);
        d0 *= d0; d1 *= d1; d2 *= d2; d3 *= d3;
        const float4* g4 = (const float4*)G1;
        const float4 g0 = g4[0], g1 = g4[1], g2 = g4[2], g3 = g4[3];
        T  = g0.x * d0 + g0.y * d1 + g0.z * d2 + g0.w * d3;
        Mx = g1.x * d0 + g1.y * d1 + g1.z * d2 + g1.w * d3;
        My = g2.x * d0 + g2.y * d1 + g2.z * d2 + g2.w * d3;
        Mz = g3.x * d0 + g3.y * d1 + g3.z * d2 + g3.w * d3;
    }

    // ---- read only the needed fields from this thread's LDS row ----
    float* row = &lds[tid * STRIDE];
    const float  pxo = row[3];                       // pos.x
    const float2 pyz = *(const float2*)&row[4];      // pos.y, pos.z
    const float4 A   = *(const float4*)&row[8];      // {s8, qw, qx, qy}
    const float4 Bv  = *(const float4*)&row[12];     // {qz, v0, v1, v2}
    const float4 C   = *(const float4*)&row[16];     // {ub, vb, wb, p}
    const float2 Dq  = *(const float2*)&row[20];     // {q, r}
    const float4 Wd  = *(const float4*)&row[28];     // {wx, wy, wz, s31}

    const float ew = A.y, ex = A.z, ey = A.w, ez = Bv.x;

    // rotation matrix from ORIGINAL quaternion
    const float r00 = ew*ew + ex*ex - ey*ey - ez*ez;
    const float r01 = 2.0f * (ex*ey - ew*ez);
    const float r02 = 2.0f * (ex*ez + ew*ey);
    const float r10 = 2.0f * (ex*ey + ew*ez);
    const float r11 = ew*ew - ex*ex + ey*ey - ez*ez;
    const float r12 = 2.0f * (ey*ez - ew*ex);
    const float r20 = 2.0f * (ex*ez - ew*ey);
    const float r21 = 2.0f * (ey*ez + ew*ex);
    const float r22 = ew*ew - ex*ex - ey*ey + ez*ez;

    // wind in body frame: R^T @ wind
    const float vwb0 = r00 * Wd.x + r10 * Wd.y + r20 * Wd.z;
    const float vwb1 = r01 * Wd.x + r11 * Wd.y + r21 * Wd.z;
    const float vwb2 = r02 * Wd.x + r12 * Wd.y + r22 * Wd.z;

    const float u_r = C.x - vwb0;
    const float v_r = C.y - vwb1;
    const float w_r = C.z - vwb2;
    const float Va = sqrtf(u_r * u_r + v_r * v_r + w_r * w_r);
    const float alpha = (u_r == 0.0f) ? PI_2F : atan2f(w_r, u_r);
    const float beta  = (Va == 0.0f) ? 0.0f : asinf(clamp1(v_r / Va));

    // body forces -> inertial, v_dot (constant across all RK4 stages)
    const float fx = -KDF * u_r;
    const float fy = -KDF * v_r;
    const float fz = -T - KDF * w_r + KHF * (u_r * u_r + v_r * v_r);
    const float vd0 = (r00 * fx + r01 * fy + r02 * fz) * INV_MASSF;
    const float vd1 = (r10 * fx + r11 * fy + r12 * fz) * INV_MASSF;
    const float vd2 = (r20 * fx + r21 * fy + r22 * fz) * INV_MASSF + GRAVF;

    // exact RK4 closed forms for pos/v (v_dot stage-constant)
    const float vn0 = Bv.y + dt * vd0;
    const float vn1 = Bv.z + dt * vd1;
    const float vn2 = Bv.w + dt * vd2;
    const float hdt2 = 0.5f * dt * dt;
    const float pn0 = pxo   + dt * Bv.y + hdt2 * vd0;
    const float pn1 = pyz.x + dt * Bv.z + hdt2 * vd1;
    const float pn2 = pyz.y + dt * Bv.w + hdt2 * vd2;

    // ---- RK4 on the coupled 7 states (accumulator form) ----
    float x0[7] = {ew, ex, ey, ez, C.w, Dq.x, Dq.y};
    float k[7], acc[7], xt[7], xn[7];
    qw_deriv(x0, Mx, My, Mz, k);
    #pragma unroll
    for (int i = 0; i < 7; ++i) { acc[i] = k[i]; xt[i] = x0[i] + h2 * k[i]; }
    qw_deriv(xt, Mx, My, Mz, k);
    #pragma unroll
    for (int i = 0; i < 7; ++i) { acc[i] += 2.0f * k[i]; xt[i] = x0[i] + h2 * k[i]; }
    qw_deriv(xt, Mx, My, Mz, k);
    #pragma unroll
    for (int i = 0; i < 7; ++i) { acc[i] += 2.0f * k[i]; xt[i] = x0[i] + dt * k[i]; }
    qw_deriv(xt, Mx, My, Mz, k);
    const float dt6 = dt / 6.0f;
    #pragma unroll
    for (int i = 0; i < 7; ++i) xn[i] = x0[i] + dt6 * (acc[i] + k[i]);

    // ---- normalize new quaternion ----
    float qw2 = xn[0], qx2 = xn[1], qy2 = xn[2], qz2 = xn[3];
    const float qi = 1.0f / sqrtf(qw2*qw2 + qx2*qx2 + qy2*qy2 + qz2*qz2);
    qw2 *= qi; qx2 *= qi; qy2 *= qi; qz2 *= qi;

    // ---- euler angles from NEW quaternion ----
    const float phi = atan2f(2.0f * (qw2 * qx2 + qy2 * qz2),
                             qw2*qw2 + qz2*qz2 - qx2*qx2 - qy2*qy2);
    const float theta = asinf(clamp1(2.0f * (qw2 * qy2 - qx2 * qz2)));
    const float psi = atan2f(2.0f * (qw2 * qz2 + qx2 * qy2),
                             qw2*qw2 + qx2*qx2 - qy2*qy2 - qz2*qz2);

    // ---- ground speed from ORIGINAL R and body velocity ----
    const float p0 = r00 * C.x + r01 * C.y + r02 * C.z;
    const float p1 = r10 * C.x + r11 * C.y + r12 * C.z;
    const float p2 = r20 * C.x + r21 * C.y + r22 * C.z;
    const float Vg = sqrtf(p0 * p0 + p1 * p1 + p2 * p2);
    const float vgs = (Vg == 0.0f) ? 1.0f : Vg;
    const float gamma = asinf(clamp1(p2 / vgs));
    const float chi = atan2f(p1, p0);

    // ---- write only changed fields back to own LDS row ----
    // untouched words 0..2, 16..18, 28..31 pass through in LDS for free
    row[3] = pn0;
    *(float4*)&row[4]  = make_float4(pn1, pn2, phi, theta);   // o4,o5,o6,o7
    *(float4*)&row[8]  = make_float4(psi, qw2, qx2, qy2);     // o8..o11
    *(float4*)&row[12] = make_float4(qz2, vn0, vn1, vn2);     // o12..o15
    row[19] = xn[4];                                          // o19
    *(float4*)&row[20] = make_float4(xn[5], xn[6], Va, Vg);   // o20..o23
    *(float4*)&row[24] = make_float4(alpha, beta, gamma, chi);// o24..o27
    __syncthreads();

    // ---- coalesced stage-out ----
    if (full) {
        float4* op4 = (float4*)(out + (size_t)row0 * 32);
        #pragma unroll
        for (int i = 0; i < 8; ++i) {
            const int f4 = i * ROWS + tid;
            const int r  = f4 >> 3;
            const int c4 = f4 & 7;
            op4[f4] = *(const float4*)&lds[r * STRIDE + c4 * 4];
        }
    } else {
        #pragma unroll
        for (int i = 0; i < 8; ++i) {
            const int f4 = i * ROWS + tid;
            const int r  = f4 >> 3;
            const int c4 = f4 & 7;
            if (row0 + r < B)
                ((float4*)out)[(size_t)(row0 + r) * 8 + c4] =
                    *(const float4*)&lds[r * STRIDE + c4 * 4];
        }
    }
}

extern "C" void kernel_launch(void* const* d_in, const int* in_sizes, int n_in,
                              void* d_out, int out_size, void* d_ws, size_t ws_size,
                              hipStream_t stream) {
    const float* state = (const float*)d_in[0];
    const float* delta = (const float*)d_in[1];
    const float* G1    = (const float*)d_in[2];
    const float* dtp   = (const float*)d_in[3];
    float* out = (float*)d_out;
    const int B = in_sizes[0] / 32;
    const int grid = (B + ROWS - 1) / ROWS;
    hipLaunchKernelGGL(qd_dynamics_kernel, dim3(grid), dim3(ROWS), 0, stream,
                       state, delta, G1, dtp, out, B);
}